// Round 12
// baseline (184.148 us; speedup 1.0000x reference)
//
#include <hip/hip_runtime.h>
#include <stdint.h>

// Problem constants
#define B_  16
#define C_  256
#define T_  2048
#define K_  1024
#define TOTAL_ELEMS 8388608   // B*C*T

typedef short bf16x8 __attribute__((ext_vector_type(8)));
typedef float f32x4 __attribute__((ext_vector_type(4)));

// ---------- packed (dist, idx) ordering helpers ----------
__device__ __forceinline__ unsigned long long pack_key(float d, int idx) {
  unsigned u = __float_as_uint(d);
  u = (u & 0x80000000u) ? ~u : (u | 0x80000000u);   // monotone map f32 -> u32
  return ((unsigned long long)u << 32) | (unsigned)idx;
}
__device__ __forceinline__ float unpack_dist(unsigned long long key) {
  unsigned du = (unsigned)(key >> 32);
  unsigned bits = (du & 0x80000000u) ? (du ^ 0x80000000u) : ~du;
  return __uint_as_float(bits);
}

__device__ __forceinline__ unsigned short f2bf_rne(float f) {
  unsigned u = __float_as_uint(f);
  unsigned r = u + 0x7FFFu + ((u >> 16) & 1u);
  return (unsigned short)(r >> 16);
}

// ---------- prep: norms (0..11) + e0 -> fragment-linear bf16 ebt (12..267) + init (268..271) ----------
// ebt layout: element (code, c) with kk=c>>5, lg=(c>>3)&3, j=c&7 stored at
// shorts[ ((kk*1024 + code)*4 + lg)*8 + j ]  -> a wave's B-fragment load is 1024B contiguous.
__global__ __launch_bounds__(256) void prep_kernel(
    const float* __restrict__ e0, const float* __restrict__ e1,
    const float* __restrict__ e2, float* __restrict__ nrm,
    unsigned short* __restrict__ ebt, uint4* __restrict__ keysM_region,
    float* __restrict__ loss_accum, unsigned* __restrict__ counter) {
  int bid = blockIdx.x;
  int tid = threadIdx.x;
  if (bid < 12) {
    int i = bid * 256 + tid;             // 0..3071
    const float* e = (i < 1024) ? e0 : (i < 2048) ? e1 : e2;
    const float* p = e + (size_t)(i & 1023) * C_;
    float s = 0.0f;
    for (int c = 0; c < C_; c += 4) {
      float4 v = *(const float4*)(p + c);
      s = fmaf(v.x, v.x, s); s = fmaf(v.y, v.y, s);
      s = fmaf(v.z, v.z, s); s = fmaf(v.w, v.w, s);
    }
    nrm[i] = s;
  } else if (bid < 268) {
    // 256 blocks x 4 codes: transpose-convert e0 into fragment-linear ebt
    int code = (bid - 12) * 4 + (tid >> 6);
    int c = (tid & 63) * 4;
    float4 v = *(const float4*)(e0 + (size_t)code * C_ + c);
    unsigned lo = (unsigned)f2bf_rne(v.x) | ((unsigned)f2bf_rne(v.y) << 16);
    unsigned hi = (unsigned)f2bf_rne(v.z) | ((unsigned)f2bf_rne(v.w) << 16);
    int kk = c >> 5, lg = (c >> 3) & 3, j = c & 7;
    *(uint2*)(ebt + ((size_t)(kk * 1024 + code) * 4 + lg) * 8 + j) = make_uint2(lo, hi);
  } else {
    int i = (bid - 268) * 256 + tid;     // 0..1023: keysM (16384 B = 1024 uint4)
    keysM_region[i] = make_uint4(0xFFFFFFFFu, 0xFFFFFFFFu, 0xFFFFFFFFu, 0xFFFFFFFFu);
    if (bid == 268 && tid == 0) { *loss_accum = 0.0f; *counter = 0u; }
  }
}

// ---------- code-to-code maps as tiled f32 GEMM + argmin ----------
__global__ __launch_bounds__(256) void map_tile_kernel(
    const float* __restrict__ e0, const float* __restrict__ e1,
    const float* __restrict__ e2, const float* __restrict__ nrm,
    unsigned long long* __restrict__ keysM) {
  __shared__ float As[16][68];
  __shared__ float Bs[16][68];
  int bid = blockIdx.x;
  int m = bid >> 8;
  int tb = bid & 255;
  int ar0 = (tb >> 4) << 6;
  int br0 = (tb & 15) << 6;
  const float* Ap = m ? e1 : e0;
  const float* Bp = m ? e2 : e1;
  const float* nB = nrm + (m + 1) * 1024;

  int tid = threadIdx.x;
  int ty = tid >> 4, tx = tid & 15;
  int srow = tid >> 2;
  int skp  = (tid & 3) << 2;

  float acc[4][4];
#pragma unroll
  for (int i = 0; i < 4; i++)
#pragma unroll
    for (int j = 0; j < 4; j++) acc[i][j] = 0.0f;

  const float* gA = Ap + (size_t)(ar0 + srow) * C_ + skp;
  const float* gB = Bp + (size_t)(br0 + srow) * C_ + skp;

  for (int kk = 0; kk < C_; kk += 16) {
    float4 av = *(const float4*)(gA + kk);
    float4 bv = *(const float4*)(gB + kk);
    __syncthreads();
    As[skp + 0][srow] = av.x; As[skp + 1][srow] = av.y;
    As[skp + 2][srow] = av.z; As[skp + 3][srow] = av.w;
    Bs[skp + 0][srow] = bv.x; Bs[skp + 1][srow] = bv.y;
    Bs[skp + 2][srow] = bv.z; Bs[skp + 3][srow] = bv.w;
    __syncthreads();
#pragma unroll
    for (int k = 0; k < 16; k++) {
      float4 a4 = *(const float4*)&As[k][ty * 4];
      float4 b4 = *(const float4*)&Bs[k][tx * 4];
      float aa[4] = {a4.x, a4.y, a4.z, a4.w};
      float bb[4] = {b4.x, b4.y, b4.z, b4.w};
#pragma unroll
      for (int i = 0; i < 4; i++)
#pragma unroll
        for (int j = 0; j < 4; j++)
          acc[i][j] = fmaf(aa[i], bb[j], acc[i][j]);
    }
  }

  float nv[4];
#pragma unroll
  for (int j = 0; j < 4; j++) nv[j] = nB[br0 + tx * 4 + j];

#pragma unroll
  for (int i = 0; i < 4; i++) {
    unsigned long long best = 0xFFFFFFFFFFFFFFFFULL;
#pragma unroll
    for (int j = 0; j < 4; j++) {
      int code = br0 + tx * 4 + j;
      float s = nv[j] - 2.0f * acc[i][j];
      unsigned long long key = pack_key(s, code);
      if (key < best) best = key;
    }
#pragma unroll
    for (int off = 1; off < 16; off <<= 1) {
      unsigned long long o = __shfl_xor(best, off, 64);
      if (o < best) best = o;
    }
    if (tx == 0)
      atomicMin(&keysM[m * 1024 + ar0 + ty * 4 + i], best);
  }
}

// ---------- layer-0 fused: MFMA distance GEMM + argmin + sum(x^2), high-occupancy ----------
// 1024 blocks x 256 threads (4 waves; __launch_bounds__(256,4) -> 4 blocks/CU, 16 waves/CU).
// Each block: 32 rows, all 1024 codes; wave w owns codes [w*256, w*256+256) -> NO duplicate
// B fetches. A (32 rows x 256 c bf16 = 16 KB) resident in LDS, k-major slots (cc*32+row)*16.
// B streamed to NAMED regs (2-step double buffer) from fragment-linear ebt (L2-resident).
// Per-thread regs ~100 (acc[2][4]=32, B 32, best 16) -> fits the 128 cap at 4 waves/SIMD.
// acc init = -||e||^2/2 so acc = -s/2; keys written directly (no atomics/init).
__global__ __launch_bounds__(256, 4) void l0_fused_kernel(
    const float* __restrict__ x, const unsigned short* __restrict__ ebt,
    const float* __restrict__ e0n, unsigned long long* __restrict__ keys,
    float* __restrict__ loss_accum) {
  __shared__ __align__(16) char Abuf[16384];
  __shared__ unsigned long long kred[32][4];
  __shared__ float red[4];

  int tid = threadIdx.x;                         // 0..255
  int l = tid & 63, w = tid >> 6;                // 4 waves, w = code quarter
  int lr = l & 15, lg = l >> 4;
  int row0 = blockIdx.x << 5;

  // ---- phase 1: x -> A_lds (transpose+cvt, k-major) + sum(x^2), non-temporal ----
  {
    int row = tid & 31;
    int cg  = tid >> 5;                          // 0..7
    int bb  = blockIdx.x >> 6;
    int t0  = (blockIdx.x & 63) << 5;
    const float* xb = x + (size_t)bb * (C_ * T_) + t0 + row;
    float sumsq = 0.0f;
#pragma unroll
    for (int i = 0; i < 4; i++) {
      int c0 = cg * 32 + i * 8;
      float v[8];
#pragma unroll
      for (int u = 0; u < 8; u++) {
        v[u] = __builtin_nontemporal_load(xb + (size_t)(c0 + u) * T_);
        sumsq = fmaf(v[u], v[u], sumsq);
      }
      unsigned pk[4];
#pragma unroll
      for (int j = 0; j < 4; j++)
        pk[j] = (unsigned)f2bf_rne(v[2 * j]) | ((unsigned)f2bf_rne(v[2 * j + 1]) << 16);
      int cc = c0 >> 3;                          // k-major slot plane 0..31
      *(uint4*)(Abuf + ((size_t)cc * 32 + row) * 16) =
          make_uint4(pk[0], pk[1], pk[2], pk[3]);
    }
    for (int off = 32; off > 0; off >>= 1) sumsq += __shfl_down(sumsq, off, 64);
    if (l == 0) red[w] = sumsq;
  }
  __syncthreads();                               // A ready
  if (tid == 0)
    atomicAdd(loss_accum, red[0] + red[1] + red[2] + red[3]);

  // per-lane base into fragment-linear ebt (code base w*256+lr, k-slot lg)
  const unsigned short* pB = ebt + ((size_t)(w * 256 + lr) * 4 + lg) * 8;

#define LOADB(s, p_, kk_) do {                                               \
    const unsigned short* q_ = pB + (size_t)(kk_) * 32768 + (size_t)(p_) * 2048; \
    s##0 = *(const bf16x8*)(q_);                                             \
    s##1 = *(const bf16x8*)(q_ + 512);                                       \
    s##2 = *(const bf16x8*)(q_ + 1024);                                      \
    s##3 = *(const bf16x8*)(q_ + 1536);                                      \
  } while (0)

#define DOKK(kk_, s) do {                                                    \
    const char* ab_ = Abuf + (size_t)(((kk_) * 4 + lg) * 32 + lr) * 16;      \
    bf16x8 a0_ = *(const bf16x8*)(ab_);                                      \
    bf16x8 a1_ = *(const bf16x8*)(ab_ + 256);                                \
    acc[0][0] = __builtin_amdgcn_mfma_f32_16x16x32_bf16(a0_, s##0, acc[0][0], 0, 0, 0); \
    acc[1][0] = __builtin_amdgcn_mfma_f32_16x16x32_bf16(a1_, s##0, acc[1][0], 0, 0, 0); \
    acc[0][1] = __builtin_amdgcn_mfma_f32_16x16x32_bf16(a0_, s##1, acc[0][1], 0, 0, 0); \
    acc[1][1] = __builtin_amdgcn_mfma_f32_16x16x32_bf16(a1_, s##1, acc[1][1], 0, 0, 0); \
    acc[0][2] = __builtin_amdgcn_mfma_f32_16x16x32_bf16(a0_, s##2, acc[0][2], 0, 0, 0); \
    acc[1][2] = __builtin_amdgcn_mfma_f32_16x16x32_bf16(a1_, s##2, acc[1][2], 0, 0, 0); \
    acc[0][3] = __builtin_amdgcn_mfma_f32_16x16x32_bf16(a0_, s##3, acc[0][3], 0, 0, 0); \
    acc[1][3] = __builtin_amdgcn_mfma_f32_16x16x32_bf16(a1_, s##3, acc[1][3], 0, 0, 0); \
  } while (0)

  f32x4 acc[2][4];
  float bestv[2][4];
  int   bestm[2][4];
#pragma unroll
  for (int mi = 0; mi < 2; mi++)
#pragma unroll
    for (int r = 0; r < 4; r++) { bestv[mi][r] = -1e30f; bestm[mi][r] = 0; }

  bf16x8 bA0, bA1, bA2, bA3, bB0, bB1, bB2, bB3;
  LOADB(bA, 0, 0);

  for (int p = 0; p < 4; p++) {                  // 4 passes of 64 codes (this wave's quarter)
#pragma unroll
    for (int ni = 0; ni < 4; ni++) {
      float iv = -0.5f * e0n[w * 256 + p * 64 + ni * 16 + lr];
      f32x4 ivv = {iv, iv, iv, iv};
      acc[0][ni] = ivv;
      acc[1][ni] = ivv;
    }
#pragma unroll
    for (int kh = 0; kh < 4; kh++) {
      const int kk0 = 2 * kh, kk1 = 2 * kh + 1;
      LOADB(bB, p, kk1);
      DOKK(kk0, bA);
      if (kk1 < 7)    { LOADB(bA, p, kk1 + 1); }
      else if (p < 3) { LOADB(bA, p + 1, 0); }
      DOKK(kk1, bB);
    }
    // fold pass into running best (strict > keeps lowest code on ties)
#pragma unroll
    for (int mi = 0; mi < 2; mi++)
#pragma unroll
      for (int r = 0; r < 4; r++)
#pragma unroll
        for (int ni = 0; ni < 4; ni++) {
          float v = acc[mi][ni][r];
          if (v > bestv[mi][r]) { bestv[mi][r] = v; bestm[mi][r] = p * 4 + ni; }
        }
  }
#undef LOADB
#undef DOKK

  // ---- epilogue: cross-lane reduce, direct keys write ----
#pragma unroll
  for (int mi = 0; mi < 2; mi++)
#pragma unroll
    for (int r = 0; r < 4; r++) {
      float sdist = -2.0f * bestv[mi][r];
      int m = bestm[mi][r];
      int code = (w << 8) | ((m >> 2) << 6) | ((m & 3) << 4) | lr;
      unsigned long long key = pack_key(sdist, code);
#pragma unroll
      for (int off = 1; off < 16; off <<= 1) {
        unsigned long long o = __shfl_xor(key, off, 64);
        if (o < key) key = o;
      }
      if (lr == 0) kred[mi * 16 + lg * 4 + r][w] = key;
    }
  __syncthreads();
  if (tid < 32) {
    unsigned long long b0 = kred[tid][0], b1 = kred[tid][1];
    unsigned long long b2 = kred[tid][2], b3 = kred[tid][3];
    if (b1 < b0) b0 = b1;
    if (b3 < b2) b2 = b3;
    keys[row0 + tid] = b0 < b2 ? b0 : b2;
  }
}

// ---------- gather output + per-(b,t) loss terms + fused finalize ----------
__global__ __launch_bounds__(256) void finish_kernel(
    const float* __restrict__ emb2,
    const unsigned long long* __restrict__ keys,
    const unsigned long long* __restrict__ keysM,
    const float* __restrict__ nrm,
    float* __restrict__ out, float* __restrict__ loss_accum,
    unsigned* __restrict__ counter) {
  __shared__ int code2_l[64];
  __shared__ float rloss[64];
  int tid = threadIdx.x;
  int b  = blockIdx.x >> 5;
  int t0 = (blockIdx.x & 31) << 6;
  int tt = tid & 63, w = tid >> 6;

  if (w == 0) {
    unsigned long long key0 = keys[(size_t)b * T_ + t0 + tt];
    int idx0 = (int)(key0 & 0xFFFFFFFFULL);
    float s0 = unpack_dist(key0);
    unsigned long long k1 = keysM[idx0];
    int c1 = (int)(k1 & 0xFFFFFFFFULL);
    unsigned long long k2 = keysM[1024 + c1];
    code2_l[tt] = (int)(k2 & 0xFFFFFFFFULL);
    rloss[tt] = s0 + nrm[idx0] + unpack_dist(k1) + nrm[1024 + c1] + unpack_dist(k2);
  }
  __syncthreads();

  float* ob = out + ((size_t)b << 19);
  int code2 = code2_l[tt];
  const float* e2row = emb2 + (size_t)code2 * C_;
  for (int c4 = w * 64; c4 < w * 64 + 64; c4 += 4) {
    float4 ev = *(const float4*)(e2row + c4);
    float evv[4] = {ev.x, ev.y, ev.z, ev.w};
#pragma unroll
    for (int u = 0; u < 4; u++)
      __builtin_nontemporal_store(evv[u], ob + (size_t)(c4 + u) * T_ + t0 + tt);
  }
  if (w == 0) {
    float tot = rloss[tt];
    for (int off = 32; off > 0; off >>= 1)
      tot += __shfl_down(tot, off, 64);
    if (tt == 0) atomicAdd(loss_accum, tot);
  }
  if (tid == 0) {
    __threadfence();
    unsigned old = atomicAdd(counter, 1u);
    if (old == 511u) {
      float L = atomicAdd(loss_accum, 0.0f);   // device-scope read
      out[TOTAL_ELEMS] = 2.0f * L / 8388608.0f;
    }
  }
}

extern "C" void kernel_launch(void* const* d_in, const int* in_sizes, int n_in,
                              void* d_out, int out_size, void* d_ws, size_t ws_size,
                              hipStream_t stream) {
  const float* x  = (const float*)d_in[0];
  const float* e0 = (const float*)d_in[1];
  const float* e1 = (const float*)d_in[2];
  const float* e2 = (const float*)d_in[3];
  float* out = (float*)d_out;
  char* ws = (char*)d_ws;

  unsigned long long* keys  = (unsigned long long*)ws;            // 262144 B
  unsigned long long* keysM = (unsigned long long*)(ws + 262144); // 16384 B
  float* nrm  = (float*)(ws + 278528);                            // 12288 B
  float* loss_accum = (float*)(ws + 290816);                      // 4 B
  unsigned* counter = (unsigned*)(ws + 290820);                   // 4 B
  unsigned short* ebt = (unsigned short*)(ws + 294912);           // 524288 B (frag-linear e0)

  prep_kernel<<<272, 256, 0, stream>>>(e0, e1, e2, nrm, ebt, (uint4*)keysM,
                                       loss_accum, counter);
  l0_fused_kernel<<<1024, 256, 0, stream>>>(x, ebt, nrm, keys, loss_accum);
  map_tile_kernel<<<512, 256, 0, stream>>>(e0, e1, e2, nrm, keysM);
  finish_kernel<<<512, 256, 0, stream>>>(e2, keys, keysM, nrm, out, loss_accum, counter);
}

// Round 13
// 157.449 us; speedup vs baseline: 1.1696x; 1.1696x over previous
//
#include <hip/hip_runtime.h>
#include <stdint.h>

// Problem constants
#define B_  16
#define C_  256
#define T_  2048
#define K_  1024
#define TOTAL_ELEMS 8388608   // B*C*T

typedef short bf16x8 __attribute__((ext_vector_type(8)));
typedef float f32x4 __attribute__((ext_vector_type(4)));

// ---------- packed (dist, idx) ordering helpers ----------
__device__ __forceinline__ unsigned long long pack_key(float d, int idx) {
  unsigned u = __float_as_uint(d);
  u = (u & 0x80000000u) ? ~u : (u | 0x80000000u);   // monotone map f32 -> u32
  return ((unsigned long long)u << 32) | (unsigned)idx;
}
__device__ __forceinline__ float unpack_dist(unsigned long long key) {
  unsigned du = (unsigned)(key >> 32);
  unsigned bits = (du & 0x80000000u) ? (du ^ 0x80000000u) : ~du;
  return __uint_as_float(bits);
}

__device__ __forceinline__ unsigned short f2bf_rne(float f) {
  unsigned u = __float_as_uint(f);
  unsigned r = u + 0x7FFFu + ((u >> 16) & 1u);
  return (unsigned short)(r >> 16);
}

// ---------- prep: norms (0..11) + e0 -> fragment-linear bf16 ebt (12..267) + init (268..271) ----------
// ebt layout: element (code, c) with kk=c>>5, lg=(c>>3)&3, j=c&7 stored at
// shorts[ ((kk*1024 + code)*4 + lg)*8 + j ]  -> a wave's B-fragment load is 1024B contiguous.
__global__ __launch_bounds__(256) void prep_kernel(
    const float* __restrict__ e0, const float* __restrict__ e1,
    const float* __restrict__ e2, float* __restrict__ nrm,
    unsigned short* __restrict__ ebt, uint4* __restrict__ keysM_region,
    float* __restrict__ loss_accum, unsigned* __restrict__ counter) {
  int bid = blockIdx.x;
  int tid = threadIdx.x;
  if (bid < 12) {
    int i = bid * 256 + tid;             // 0..3071
    const float* e = (i < 1024) ? e0 : (i < 2048) ? e1 : e2;
    const float* p = e + (size_t)(i & 1023) * C_;
    float s = 0.0f;
    for (int c = 0; c < C_; c += 4) {
      float4 v = *(const float4*)(p + c);
      s = fmaf(v.x, v.x, s); s = fmaf(v.y, v.y, s);
      s = fmaf(v.z, v.z, s); s = fmaf(v.w, v.w, s);
    }
    nrm[i] = s;
  } else if (bid < 268) {
    // 256 blocks x 4 codes: transpose-convert e0 into fragment-linear ebt
    int code = (bid - 12) * 4 + (tid >> 6);
    int c = (tid & 63) * 4;
    float4 v = *(const float4*)(e0 + (size_t)code * C_ + c);
    unsigned lo = (unsigned)f2bf_rne(v.x) | ((unsigned)f2bf_rne(v.y) << 16);
    unsigned hi = (unsigned)f2bf_rne(v.z) | ((unsigned)f2bf_rne(v.w) << 16);
    int kk = c >> 5, lg = (c >> 3) & 3, j = c & 7;
    *(uint2*)(ebt + ((size_t)(kk * 1024 + code) * 4 + lg) * 8 + j) = make_uint2(lo, hi);
  } else {
    int i = (bid - 268) * 256 + tid;     // 0..1023: keysM (16384 B = 1024 uint4)
    keysM_region[i] = make_uint4(0xFFFFFFFFu, 0xFFFFFFFFu, 0xFFFFFFFFu, 0xFFFFFFFFu);
    if (bid == 268 && tid == 0) { *loss_accum = 0.0f; *counter = 0u; }
  }
}

// ---------- code-to-code maps as tiled f32 GEMM + argmin ----------
__global__ __launch_bounds__(256) void map_tile_kernel(
    const float* __restrict__ e0, const float* __restrict__ e1,
    const float* __restrict__ e2, const float* __restrict__ nrm,
    unsigned long long* __restrict__ keysM) {
  __shared__ float As[16][68];
  __shared__ float Bs[16][68];
  int bid = blockIdx.x;
  int m = bid >> 8;
  int tb = bid & 255;
  int ar0 = (tb >> 4) << 6;
  int br0 = (tb & 15) << 6;
  const float* Ap = m ? e1 : e0;
  const float* Bp = m ? e2 : e1;
  const float* nB = nrm + (m + 1) * 1024;

  int tid = threadIdx.x;
  int ty = tid >> 4, tx = tid & 15;
  int srow = tid >> 2;
  int skp  = (tid & 3) << 2;

  float acc[4][4];
#pragma unroll
  for (int i = 0; i < 4; i++)
#pragma unroll
    for (int j = 0; j < 4; j++) acc[i][j] = 0.0f;

  const float* gA = Ap + (size_t)(ar0 + srow) * C_ + skp;
  const float* gB = Bp + (size_t)(br0 + srow) * C_ + skp;

  for (int kk = 0; kk < C_; kk += 16) {
    float4 av = *(const float4*)(gA + kk);
    float4 bv = *(const float4*)(gB + kk);
    __syncthreads();
    As[skp + 0][srow] = av.x; As[skp + 1][srow] = av.y;
    As[skp + 2][srow] = av.z; As[skp + 3][srow] = av.w;
    Bs[skp + 0][srow] = bv.x; Bs[skp + 1][srow] = bv.y;
    Bs[skp + 2][srow] = bv.z; Bs[skp + 3][srow] = bv.w;
    __syncthreads();
#pragma unroll
    for (int k = 0; k < 16; k++) {
      float4 a4 = *(const float4*)&As[k][ty * 4];
      float4 b4 = *(const float4*)&Bs[k][tx * 4];
      float aa[4] = {a4.x, a4.y, a4.z, a4.w};
      float bb[4] = {b4.x, b4.y, b4.z, b4.w};
#pragma unroll
      for (int i = 0; i < 4; i++)
#pragma unroll
        for (int j = 0; j < 4; j++)
          acc[i][j] = fmaf(aa[i], bb[j], acc[i][j]);
    }
  }

  float nv[4];
#pragma unroll
  for (int j = 0; j < 4; j++) nv[j] = nB[br0 + tx * 4 + j];

#pragma unroll
  for (int i = 0; i < 4; i++) {
    unsigned long long best = 0xFFFFFFFFFFFFFFFFULL;
#pragma unroll
    for (int j = 0; j < 4; j++) {
      int code = br0 + tx * 4 + j;
      float s = nv[j] - 2.0f * acc[i][j];
      unsigned long long key = pack_key(s, code);
      if (key < best) best = key;
    }
#pragma unroll
    for (int off = 1; off < 16; off <<= 1) {
      unsigned long long o = __shfl_xor(best, off, 64);
      if (o < best) best = o;
    }
    if (tx == 0)
      atomicMin(&keysM[m * 1024 + ar0 + ty * 4 + i], best);
  }
}

// ---------- layer-0 fused: MFMA distance GEMM + argmin + sum(x^2), deep-ILP ----------
// 512 blocks x 256 threads, __launch_bounds__(256,2) (the ONLY proven-safe bound:
// VGPR budget 256, 2 blocks/CU). Each block: 64 rows, all 1024 codes; wave w owns
// codes [w*256, w*256+256) -> no duplicate B fetches (256 MB L2 total). A (64 rows x
// 256 c bf16 = 32 KB) in LDS, k-major slots (cc*64+row)*16, conflict-free. B streamed
// to NAMED regs at kk-PAIR granularity (bA0..7 / bB0..7, 1-pair-ahead prefetch):
// each prefetch window covers 32 MFMAs (~320 cyc across 2 waves/SIMD) ~ L2 latency.
// acc[4][4] init = -||e||^2/2 so acc = -s/2; keys written directly.
__global__ __launch_bounds__(256, 2) void l0_fused_kernel(
    const float* __restrict__ x, const unsigned short* __restrict__ ebt,
    const float* __restrict__ e0n, unsigned long long* __restrict__ keys,
    float* __restrict__ loss_accum) {
  __shared__ __align__(16) char Abuf[32768];
  __shared__ unsigned long long kred[64][4];
  __shared__ float red[4];

  int tid = threadIdx.x;                         // 0..255
  int l = tid & 63, w = tid >> 6;                // 4 waves, w = code quarter
  int lr = l & 15, lg = l >> 4;
  int row0 = blockIdx.x << 6;

  // ---- phase 1: x -> A_lds (transpose+cvt, k-major) + sum(x^2), non-temporal ----
  {
    int row = tid & 63;
    int cg  = tid >> 6;                          // 0..3
    int bb  = blockIdx.x >> 5;
    int t0  = (blockIdx.x & 31) << 6;
    const float* xb = x + (size_t)bb * (C_ * T_) + t0 + row;
    float sumsq = 0.0f;
#pragma unroll
    for (int i = 0; i < 8; i++) {
      int c0 = cg * 64 + i * 8;
      float v[8];
#pragma unroll
      for (int u = 0; u < 8; u++) {
        v[u] = __builtin_nontemporal_load(xb + (size_t)(c0 + u) * T_);
        sumsq = fmaf(v[u], v[u], sumsq);
      }
      unsigned pk[4];
#pragma unroll
      for (int j = 0; j < 4; j++)
        pk[j] = (unsigned)f2bf_rne(v[2 * j]) | ((unsigned)f2bf_rne(v[2 * j + 1]) << 16);
      int cc = c0 >> 3;                          // k-major slot plane 0..31
      *(uint4*)(Abuf + ((size_t)cc * 64 + row) * 16) =
          make_uint4(pk[0], pk[1], pk[2], pk[3]);
    }
    for (int off = 32; off > 0; off >>= 1) sumsq += __shfl_down(sumsq, off, 64);
    if (l == 0) red[w] = sumsq;
  }
  __syncthreads();                               // A ready
  if (tid == 0)
    atomicAdd(loss_accum, red[0] + red[1] + red[2] + red[3]);

  // norms for this wave's code quarter
  float nv[4][4];
#pragma unroll
  for (int p = 0; p < 4; p++)
#pragma unroll
    for (int ni = 0; ni < 4; ni++)
      nv[p][ni] = e0n[w * 256 + p * 64 + ni * 16 + lr];

  // per-lane base into fragment-linear ebt (code base w*256+lr, k-slot lg)
  const unsigned short* pB = ebt + ((size_t)(w * 256 + lr) * 4 + lg) * 8;

  // load a kk-PAIR (8 fragments) into named set s##0..7
#define LOADB2(s, p_, pr_) do {                                              \
    const unsigned short* q_ = pB + (size_t)(pr_) * 65536 + (size_t)(p_) * 2048; \
    s##0 = *(const bf16x8*)(q_);                                             \
    s##1 = *(const bf16x8*)(q_ + 512);                                       \
    s##2 = *(const bf16x8*)(q_ + 1024);                                      \
    s##3 = *(const bf16x8*)(q_ + 1536);                                      \
    s##4 = *(const bf16x8*)(q_ + 32768);                                     \
    s##5 = *(const bf16x8*)(q_ + 32768 + 512);                               \
    s##6 = *(const bf16x8*)(q_ + 32768 + 1024);                              \
    s##7 = *(const bf16x8*)(q_ + 32768 + 1536);                              \
  } while (0)

  // 16 MFMAs of one kk against B frags f0..f3
#define DOKK1(kk_, f0, f1, f2, f3) do {                                      \
    const char* ab_ = Abuf + (size_t)(((kk_) * 4 + lg) * 64 + lr) * 16;      \
    bf16x8 a0_ = *(const bf16x8*)(ab_);                                      \
    bf16x8 a1_ = *(const bf16x8*)(ab_ + 256);                                \
    bf16x8 a2_ = *(const bf16x8*)(ab_ + 512);                                \
    bf16x8 a3_ = *(const bf16x8*)(ab_ + 768);                                \
    acc[0][0] = __builtin_amdgcn_mfma_f32_16x16x32_bf16(a0_, f0, acc[0][0], 0, 0, 0); \
    acc[1][0] = __builtin_amdgcn_mfma_f32_16x16x32_bf16(a1_, f0, acc[1][0], 0, 0, 0); \
    acc[2][0] = __builtin_amdgcn_mfma_f32_16x16x32_bf16(a2_, f0, acc[2][0], 0, 0, 0); \
    acc[3][0] = __builtin_amdgcn_mfma_f32_16x16x32_bf16(a3_, f0, acc[3][0], 0, 0, 0); \
    acc[0][1] = __builtin_amdgcn_mfma_f32_16x16x32_bf16(a0_, f1, acc[0][1], 0, 0, 0); \
    acc[1][1] = __builtin_amdgcn_mfma_f32_16x16x32_bf16(a1_, f1, acc[1][1], 0, 0, 0); \
    acc[2][1] = __builtin_amdgcn_mfma_f32_16x16x32_bf16(a2_, f1, acc[2][1], 0, 0, 0); \
    acc[3][1] = __builtin_amdgcn_mfma_f32_16x16x32_bf16(a3_, f1, acc[3][1], 0, 0, 0); \
    acc[0][2] = __builtin_amdgcn_mfma_f32_16x16x32_bf16(a0_, f2, acc[0][2], 0, 0, 0); \
    acc[1][2] = __builtin_amdgcn_mfma_f32_16x16x32_bf16(a1_, f2, acc[1][2], 0, 0, 0); \
    acc[2][2] = __builtin_amdgcn_mfma_f32_16x16x32_bf16(a2_, f2, acc[2][2], 0, 0, 0); \
    acc[3][2] = __builtin_amdgcn_mfma_f32_16x16x32_bf16(a3_, f2, acc[3][2], 0, 0, 0); \
    acc[0][3] = __builtin_amdgcn_mfma_f32_16x16x32_bf16(a0_, f3, acc[0][3], 0, 0, 0); \
    acc[1][3] = __builtin_amdgcn_mfma_f32_16x16x32_bf16(a1_, f3, acc[1][3], 0, 0, 0); \
    acc[2][3] = __builtin_amdgcn_mfma_f32_16x16x32_bf16(a2_, f3, acc[2][3], 0, 0, 0); \
    acc[3][3] = __builtin_amdgcn_mfma_f32_16x16x32_bf16(a3_, f3, acc[3][3], 0, 0, 0); \
  } while (0)

  // a full kk-pair (32 MFMAs) against named set s##0..7
#define DOPAIR(pr_, s) do {                                                  \
    DOKK1(2 * (pr_), s##0, s##1, s##2, s##3);                                \
    DOKK1(2 * (pr_) + 1, s##4, s##5, s##6, s##7);                            \
  } while (0)

  f32x4 acc[4][4];
  float bestv[4][4];
  int   bestm[4][4];
#pragma unroll
  for (int mi = 0; mi < 4; mi++)
#pragma unroll
    for (int r = 0; r < 4; r++) { bestv[mi][r] = -1e30f; bestm[mi][r] = 0; }

  bf16x8 bA0, bA1, bA2, bA3, bA4, bA5, bA6, bA7;
  bf16x8 bB0, bB1, bB2, bB3, bB4, bB5, bB6, bB7;
  LOADB2(bA, 0, 0);

#pragma unroll
  for (int p = 0; p < 4; p++) {                  // 4 passes of 64 codes (this wave's quarter)
#pragma unroll
    for (int ni = 0; ni < 4; ni++) {
      float iv = -0.5f * nv[p][ni];
      f32x4 ivv = {iv, iv, iv, iv};
#pragma unroll
      for (int mi = 0; mi < 4; mi++) acc[mi][ni] = ivv;
    }
    LOADB2(bB, p, 1);
    DOPAIR(0, bA);
    LOADB2(bA, p, 2);
    DOPAIR(1, bB);
    LOADB2(bB, p, 3);
    DOPAIR(2, bA);
    if (p < 3) LOADB2(bA, p + 1, 0);
    DOPAIR(3, bB);
    // fold pass into running best (strict > keeps lowest code on ties)
#pragma unroll
    for (int mi = 0; mi < 4; mi++)
#pragma unroll
      for (int r = 0; r < 4; r++)
#pragma unroll
        for (int ni = 0; ni < 4; ni++) {
          float v = acc[mi][ni][r];
          if (v > bestv[mi][r]) { bestv[mi][r] = v; bestm[mi][r] = p * 4 + ni; }
        }
  }
#undef LOADB2
#undef DOKK1
#undef DOPAIR

  // ---- epilogue: cross-lane reduce, direct keys write ----
#pragma unroll
  for (int mi = 0; mi < 4; mi++)
#pragma unroll
    for (int r = 0; r < 4; r++) {
      float sdist = -2.0f * bestv[mi][r];
      int m = bestm[mi][r];
      int code = (w << 8) | ((m >> 2) << 6) | ((m & 3) << 4) | lr;
      unsigned long long key = pack_key(sdist, code);
#pragma unroll
      for (int off = 1; off < 16; off <<= 1) {
        unsigned long long o = __shfl_xor(key, off, 64);
        if (o < key) key = o;
      }
      if (lr == 0) kred[mi * 16 + lg * 4 + r][w] = key;
    }
  __syncthreads();
  if (tid < 64) {
    unsigned long long b0 = kred[tid][0], b1 = kred[tid][1];
    unsigned long long b2 = kred[tid][2], b3 = kred[tid][3];
    if (b1 < b0) b0 = b1;
    if (b3 < b2) b2 = b3;
    keys[row0 + tid] = b0 < b2 ? b0 : b2;
  }
}

// ---------- gather output + per-(b,t) loss terms + fused finalize ----------
__global__ __launch_bounds__(256) void finish_kernel(
    const float* __restrict__ emb2,
    const unsigned long long* __restrict__ keys,
    const unsigned long long* __restrict__ keysM,
    const float* __restrict__ nrm,
    float* __restrict__ out, float* __restrict__ loss_accum,
    unsigned* __restrict__ counter) {
  __shared__ int code2_l[64];
  __shared__ float rloss[64];
  int tid = threadIdx.x;
  int b  = blockIdx.x >> 5;
  int t0 = (blockIdx.x & 31) << 6;
  int tt = tid & 63, w = tid >> 6;

  if (w == 0) {
    unsigned long long key0 = keys[(size_t)b * T_ + t0 + tt];
    int idx0 = (int)(key0 & 0xFFFFFFFFULL);
    float s0 = unpack_dist(key0);
    unsigned long long k1 = keysM[idx0];
    int c1 = (int)(k1 & 0xFFFFFFFFULL);
    unsigned long long k2 = keysM[1024 + c1];
    code2_l[tt] = (int)(k2 & 0xFFFFFFFFULL);
    rloss[tt] = s0 + nrm[idx0] + unpack_dist(k1) + nrm[1024 + c1] + unpack_dist(k2);
  }
  __syncthreads();

  float* ob = out + ((size_t)b << 19);
  int code2 = code2_l[tt];
  const float* e2row = emb2 + (size_t)code2 * C_;
  for (int c4 = w * 64; c4 < w * 64 + 64; c4 += 4) {
    float4 ev = *(const float4*)(e2row + c4);
    float evv[4] = {ev.x, ev.y, ev.z, ev.w};
#pragma unroll
    for (int u = 0; u < 4; u++)
      __builtin_nontemporal_store(evv[u], ob + (size_t)(c4 + u) * T_ + t0 + tt);
  }
  if (w == 0) {
    float tot = rloss[tt];
    for (int off = 32; off > 0; off >>= 1)
      tot += __shfl_down(tot, off, 64);
    if (tt == 0) atomicAdd(loss_accum, tot);
  }
  if (tid == 0) {
    __threadfence();
    unsigned old = atomicAdd(counter, 1u);
    if (old == 511u) {
      float L = atomicAdd(loss_accum, 0.0f);   // device-scope read
      out[TOTAL_ELEMS] = 2.0f * L / 8388608.0f;
    }
  }
}

extern "C" void kernel_launch(void* const* d_in, const int* in_sizes, int n_in,
                              void* d_out, int out_size, void* d_ws, size_t ws_size,
                              hipStream_t stream) {
  const float* x  = (const float*)d_in[0];
  const float* e0 = (const float*)d_in[1];
  const float* e1 = (const float*)d_in[2];
  const float* e2 = (const float*)d_in[3];
  float* out = (float*)d_out;
  char* ws = (char*)d_ws;

  unsigned long long* keys  = (unsigned long long*)ws;            // 262144 B
  unsigned long long* keysM = (unsigned long long*)(ws + 262144); // 16384 B
  float* nrm  = (float*)(ws + 278528);                            // 12288 B
  float* loss_accum = (float*)(ws + 290816);                      // 4 B
  unsigned* counter = (unsigned*)(ws + 290820);                   // 4 B
  unsigned short* ebt = (unsigned short*)(ws + 294912);           // 524288 B (frag-linear e0)

  prep_kernel<<<272, 256, 0, stream>>>(e0, e1, e2, nrm, ebt, (uint4*)keysM,
                                       loss_accum, counter);
  l0_fused_kernel<<<512, 256, 0, stream>>>(x, ebt, nrm, keys, loss_accum);
  map_tile_kernel<<<512, 256, 0, stream>>>(e0, e1, e2, nrm, keysM);
  finish_kernel<<<512, 256, 0, stream>>>(e2, keys, keysM, nrm, out, loss_accum, counter);
}

// Round 14
// 107.998 us; speedup vs baseline: 1.7051x; 1.4579x over previous
//
#include <hip/hip_runtime.h>
#include <stdint.h>

// Problem constants
#define B_  16
#define C_  256
#define T_  2048
#define K_  1024
#define TOTAL_ELEMS 8388608   // B*C*T

typedef short bf16x8 __attribute__((ext_vector_type(8)));
typedef float f32x4 __attribute__((ext_vector_type(4)));

// ---------- packed (dist, idx) ordering helpers ----------
__device__ __forceinline__ unsigned long long pack_key(float d, int idx) {
  unsigned u = __float_as_uint(d);
  u = (u & 0x80000000u) ? ~u : (u | 0x80000000u);   // monotone map f32 -> u32
  return ((unsigned long long)u << 32) | (unsigned)idx;
}
__device__ __forceinline__ float unpack_dist(unsigned long long key) {
  unsigned du = (unsigned)(key >> 32);
  unsigned bits = (du & 0x80000000u) ? (du ^ 0x80000000u) : ~du;
  return __uint_as_float(bits);
}

__device__ __forceinline__ unsigned short f2bf_rne(float f) {
  unsigned u = __float_as_uint(f);
  unsigned r = u + 0x7FFFu + ((u >> 16) & 1u);
  return (unsigned short)(r >> 16);
}

// ---------- prep: norms (0..11) + e0 -> fragment-linear bf16 ebt (12..267) + init (268..335) ----------
// ebt layout: element (code, c) with kk=c>>5, lg=(c>>3)&3, j=c&7 stored at
// shorts[ ((kk*1024 + code)*4 + lg)*8 + j ]  -> a wave's B-fragment load is 1024B contiguous.
__global__ __launch_bounds__(256) void prep_kernel(
    const float* __restrict__ e0, const float* __restrict__ e1,
    const float* __restrict__ e2, float* __restrict__ nrm,
    unsigned short* __restrict__ ebt, uint4* __restrict__ keys_region,
    float* __restrict__ loss_accum, unsigned* __restrict__ counter) {
  int bid = blockIdx.x;
  int tid = threadIdx.x;
  if (bid < 12) {
    int i = bid * 256 + tid;             // 0..3071
    const float* e = (i < 1024) ? e0 : (i < 2048) ? e1 : e2;
    const float* p = e + (size_t)(i & 1023) * C_;
    float s = 0.0f;
    for (int c = 0; c < C_; c += 4) {
      float4 v = *(const float4*)(p + c);
      s = fmaf(v.x, v.x, s); s = fmaf(v.y, v.y, s);
      s = fmaf(v.z, v.z, s); s = fmaf(v.w, v.w, s);
    }
    nrm[i] = s;
  } else if (bid < 268) {
    // 256 blocks x 4 codes: transpose-convert e0 into fragment-linear ebt
    int code = (bid - 12) * 4 + (tid >> 6);
    int c = (tid & 63) * 4;
    float4 v = *(const float4*)(e0 + (size_t)code * C_ + c);
    unsigned lo = (unsigned)f2bf_rne(v.x) | ((unsigned)f2bf_rne(v.y) << 16);
    unsigned hi = (unsigned)f2bf_rne(v.z) | ((unsigned)f2bf_rne(v.w) << 16);
    int kk = c >> 5, lg = (c >> 3) & 3, j = c & 7;
    *(uint2*)(ebt + ((size_t)(kk * 1024 + code) * 4 + lg) * 8 + j) = make_uint2(lo, hi);
  } else {
    // init keys (262144 B) + keysM (16384 B) = 17408 uint4, and loss/counter
    int i = (bid - 268) * 256 + tid;     // 0..17407
    keys_region[i] = make_uint4(0xFFFFFFFFu, 0xFFFFFFFFu, 0xFFFFFFFFu, 0xFFFFFFFFu);
    if (bid == 268 && tid == 0) { *loss_accum = 0.0f; *counter = 0u; }
  }
}

// ---------- code-to-code maps as tiled f32 GEMM + argmin ----------
__global__ __launch_bounds__(256) void map_tile_kernel(
    const float* __restrict__ e0, const float* __restrict__ e1,
    const float* __restrict__ e2, const float* __restrict__ nrm,
    unsigned long long* __restrict__ keysM) {
  __shared__ float As[16][68];
  __shared__ float Bs[16][68];
  int bid = blockIdx.x;
  int m = bid >> 8;
  int tb = bid & 255;
  int ar0 = (tb >> 4) << 6;
  int br0 = (tb & 15) << 6;
  const float* Ap = m ? e1 : e0;
  const float* Bp = m ? e2 : e1;
  const float* nB = nrm + (m + 1) * 1024;

  int tid = threadIdx.x;
  int ty = tid >> 4, tx = tid & 15;
  int srow = tid >> 2;
  int skp  = (tid & 3) << 2;

  float acc[4][4];
#pragma unroll
  for (int i = 0; i < 4; i++)
#pragma unroll
    for (int j = 0; j < 4; j++) acc[i][j] = 0.0f;

  const float* gA = Ap + (size_t)(ar0 + srow) * C_ + skp;
  const float* gB = Bp + (size_t)(br0 + srow) * C_ + skp;

  for (int kk = 0; kk < C_; kk += 16) {
    float4 av = *(const float4*)(gA + kk);
    float4 bv = *(const float4*)(gB + kk);
    __syncthreads();
    As[skp + 0][srow] = av.x; As[skp + 1][srow] = av.y;
    As[skp + 2][srow] = av.z; As[skp + 3][srow] = av.w;
    Bs[skp + 0][srow] = bv.x; Bs[skp + 1][srow] = bv.y;
    Bs[skp + 2][srow] = bv.z; Bs[skp + 3][srow] = bv.w;
    __syncthreads();
#pragma unroll
    for (int k = 0; k < 16; k++) {
      float4 a4 = *(const float4*)&As[k][ty * 4];
      float4 b4 = *(const float4*)&Bs[k][tx * 4];
      float aa[4] = {a4.x, a4.y, a4.z, a4.w};
      float bb[4] = {b4.x, b4.y, b4.z, b4.w};
#pragma unroll
      for (int i = 0; i < 4; i++)
#pragma unroll
        for (int j = 0; j < 4; j++)
          acc[i][j] = fmaf(aa[i], bb[j], acc[i][j]);
    }
  }

  float nv[4];
#pragma unroll
  for (int j = 0; j < 4; j++) nv[j] = nB[br0 + tx * 4 + j];

#pragma unroll
  for (int i = 0; i < 4; i++) {
    unsigned long long best = 0xFFFFFFFFFFFFFFFFULL;
#pragma unroll
    for (int j = 0; j < 4; j++) {
      int code = br0 + tx * 4 + j;
      float s = nv[j] - 2.0f * acc[i][j];
      unsigned long long key = pack_key(s, code);
      if (key < best) best = key;
    }
#pragma unroll
    for (int off = 1; off < 16; off <<= 1) {
      unsigned long long o = __shfl_xor(best, off, 64);
      if (o < best) best = o;
    }
    if (tx == 0)
      atomicMin(&keysM[m * 1024 + ar0 + ty * 4 + i], best);
  }
}

// ---------- layer-0 fused: MFMA distance GEMM + argmin + sum(x^2), occupancy-driven ----------
// 2048 blocks (= 512 row-tiles x 4 code-quarters; bid = q*512 + mb so the 4 blocks of a
// row-tile share an XCD -> x re-reads hit L2). Block: 64 rows x 256 codes, 4 waves; wave w
// owns codes [q*256 + w*64, +64). A (64x256 bf16 = 32 KB) in LDS k-major, conflict-free.
// B single-kk named double-buffer (8 frags = 32 arch VGPRs; total arch ~80 < the 128 cap
// -> no spill, r11-proven profile). 4 blocks/CU resident (LDS-limited) = 16 waves/CU:
// latency hidden by wave interleave, not prefetch depth. acc init = -||e||^2/2 so
// acc = -s/2; best folded once at the end; keys via atomicMin (init 0xFF in prep).
__global__ __launch_bounds__(256, 2) void l0_fused_kernel(
    const float* __restrict__ x, const unsigned short* __restrict__ ebt,
    const float* __restrict__ e0n, unsigned long long* __restrict__ keys,
    float* __restrict__ loss_accum) {
  __shared__ __align__(16) char Abuf[32768];
  __shared__ unsigned long long kred[64][4];
  __shared__ float red[4];

  int tid = threadIdx.x;                         // 0..255
  int l = tid & 63, w = tid >> 6;                // 4 waves, w = 64-code slice
  int lr = l & 15, lg = l >> 4;
  int q  = blockIdx.x >> 9;                      // code quarter 0..3
  int mb = blockIdx.x & 511;                     // row tile 0..511
  int row0 = mb << 6;

  // ---- phase 1: x -> A_lds (transpose+cvt, k-major) + sum(x^2) (q==0 only) ----
  {
    int row = tid & 63;
    int cg  = tid >> 6;                          // 0..3
    int bb  = mb >> 5;
    int t0  = (mb & 31) << 6;
    const float* xb = x + (size_t)bb * (C_ * T_) + t0 + row;
    float sumsq = 0.0f;
#pragma unroll
    for (int i = 0; i < 8; i++) {
      int c0 = cg * 64 + i * 8;
      float v[8];
#pragma unroll
      for (int u = 0; u < 8; u++) {
        v[u] = xb[(size_t)(c0 + u) * T_];
        sumsq = fmaf(v[u], v[u], sumsq);
      }
      unsigned pk[4];
#pragma unroll
      for (int j = 0; j < 4; j++)
        pk[j] = (unsigned)f2bf_rne(v[2 * j]) | ((unsigned)f2bf_rne(v[2 * j + 1]) << 16);
      int cc = c0 >> 3;                          // k-major slot plane 0..31
      *(uint4*)(Abuf + ((size_t)cc * 64 + row) * 16) =
          make_uint4(pk[0], pk[1], pk[2], pk[3]);
    }
    for (int off = 32; off > 0; off >>= 1) sumsq += __shfl_down(sumsq, off, 64);
    if (l == 0) red[w] = sumsq;
  }
  __syncthreads();                               // A ready
  if (q == 0 && tid == 0)
    atomicAdd(loss_accum, red[0] + red[1] + red[2] + red[3]);

  // per-lane base into fragment-linear ebt (code base q*256 + w*64 + lr, k-slot lg)
  const unsigned short* pB = ebt + ((size_t)((q << 8) + w * 64 + lr) * 4 + lg) * 8;

  // load one kk (4 fragments) into named set s##0..3
#define LOADB(s, kk_) do {                                                   \
    const unsigned short* q_ = pB + (size_t)(kk_) * 32768;                   \
    s##0 = *(const bf16x8*)(q_);                                             \
    s##1 = *(const bf16x8*)(q_ + 512);                                       \
    s##2 = *(const bf16x8*)(q_ + 1024);                                      \
    s##3 = *(const bf16x8*)(q_ + 1536);                                      \
  } while (0)

  // one kk: 4 named A-frag loads + 16 MFMAs against named B set
#define DOKK(kk_, s) do {                                                    \
    const char* ab_ = Abuf + (size_t)(((kk_) * 4 + lg) * 64 + lr) * 16;      \
    bf16x8 a0_ = *(const bf16x8*)(ab_);                                      \
    bf16x8 a1_ = *(const bf16x8*)(ab_ + 256);                                \
    bf16x8 a2_ = *(const bf16x8*)(ab_ + 512);                                \
    bf16x8 a3_ = *(const bf16x8*)(ab_ + 768);                                \
    acc[0][0] = __builtin_amdgcn_mfma_f32_16x16x32_bf16(a0_, s##0, acc[0][0], 0, 0, 0); \
    acc[1][0] = __builtin_amdgcn_mfma_f32_16x16x32_bf16(a1_, s##0, acc[1][0], 0, 0, 0); \
    acc[2][0] = __builtin_amdgcn_mfma_f32_16x16x32_bf16(a2_, s##0, acc[2][0], 0, 0, 0); \
    acc[3][0] = __builtin_amdgcn_mfma_f32_16x16x32_bf16(a3_, s##0, acc[3][0], 0, 0, 0); \
    acc[0][1] = __builtin_amdgcn_mfma_f32_16x16x32_bf16(a0_, s##1, acc[0][1], 0, 0, 0); \
    acc[1][1] = __builtin_amdgcn_mfma_f32_16x16x32_bf16(a1_, s##1, acc[1][1], 0, 0, 0); \
    acc[2][1] = __builtin_amdgcn_mfma_f32_16x16x32_bf16(a2_, s##1, acc[2][1], 0, 0, 0); \
    acc[3][1] = __builtin_amdgcn_mfma_f32_16x16x32_bf16(a3_, s##1, acc[3][1], 0, 0, 0); \
    acc[0][2] = __builtin_amdgcn_mfma_f32_16x16x32_bf16(a0_, s##2, acc[0][2], 0, 0, 0); \
    acc[1][2] = __builtin_amdgcn_mfma_f32_16x16x32_bf16(a1_, s##2, acc[1][2], 0, 0, 0); \
    acc[2][2] = __builtin_amdgcn_mfma_f32_16x16x32_bf16(a2_, s##2, acc[2][2], 0, 0, 0); \
    acc[3][2] = __builtin_amdgcn_mfma_f32_16x16x32_bf16(a3_, s##2, acc[3][2], 0, 0, 0); \
    acc[0][3] = __builtin_amdgcn_mfma_f32_16x16x32_bf16(a0_, s##3, acc[0][3], 0, 0, 0); \
    acc[1][3] = __builtin_amdgcn_mfma_f32_16x16x32_bf16(a1_, s##3, acc[1][3], 0, 0, 0); \
    acc[2][3] = __builtin_amdgcn_mfma_f32_16x16x32_bf16(a2_, s##3, acc[2][3], 0, 0, 0); \
    acc[3][3] = __builtin_amdgcn_mfma_f32_16x16x32_bf16(a3_, s##3, acc[3][3], 0, 0, 0); \
  } while (0)

  f32x4 acc[4][4];
  // init acc with -||e||^2 / 2 for this wave's 64 codes
#pragma unroll
  for (int ni = 0; ni < 4; ni++) {
    float iv = -0.5f * e0n[(q << 8) + w * 64 + ni * 16 + lr];
    f32x4 ivv = {iv, iv, iv, iv};
#pragma unroll
    for (int mi = 0; mi < 4; mi++) acc[mi][ni] = ivv;
  }

  bf16x8 bA0, bA1, bA2, bA3, bB0, bB1, bB2, bB3;
  LOADB(bA, 0);
  LOADB(bB, 1); DOKK(0, bA);
  LOADB(bA, 2); DOKK(1, bB);
  LOADB(bB, 3); DOKK(2, bA);
  LOADB(bA, 4); DOKK(3, bB);
  LOADB(bB, 5); DOKK(4, bA);
  LOADB(bA, 6); DOKK(5, bB);
  LOADB(bB, 7); DOKK(6, bA);
  DOKK(7, bB);
#undef LOADB
#undef DOKK

  // ---- epilogue: fold acc -> per-row best, cross-lane reduce, atomicMin keys ----
#pragma unroll
  for (int mi = 0; mi < 4; mi++) {
#pragma unroll
    for (int r = 0; r < 4; r++) {
      unsigned long long best = 0xFFFFFFFFFFFFFFFFULL;
#pragma unroll
      for (int ni = 0; ni < 4; ni++) {
        int code = (q << 8) | (w << 6) | (ni << 4) | lr;
        unsigned long long key = pack_key(-2.0f * acc[mi][ni][r], code);
        if (key < best) best = key;
      }
#pragma unroll
      for (int off = 1; off < 16; off <<= 1) {
        unsigned long long o = __shfl_xor(best, off, 64);
        if (o < best) best = o;
      }
      if (lr == 0) kred[mi * 16 + lg * 4 + r][w] = best;
    }
  }
  __syncthreads();
  if (tid < 64) {
    unsigned long long b0 = kred[tid][0], b1 = kred[tid][1];
    unsigned long long b2 = kred[tid][2], b3 = kred[tid][3];
    if (b1 < b0) b0 = b1;
    if (b3 < b2) b2 = b3;
    atomicMin(&keys[row0 + tid], b0 < b2 ? b0 : b2);
  }
}

// ---------- gather output + per-(b,t) loss terms + fused finalize ----------
__global__ __launch_bounds__(256) void finish_kernel(
    const float* __restrict__ emb2,
    const unsigned long long* __restrict__ keys,
    const unsigned long long* __restrict__ keysM,
    const float* __restrict__ nrm,
    float* __restrict__ out, float* __restrict__ loss_accum,
    unsigned* __restrict__ counter) {
  __shared__ int code2_l[64];
  __shared__ float rloss[64];
  int tid = threadIdx.x;
  int b  = blockIdx.x >> 5;
  int t0 = (blockIdx.x & 31) << 6;
  int tt = tid & 63, w = tid >> 6;

  if (w == 0) {
    unsigned long long key0 = keys[(size_t)b * T_ + t0 + tt];
    int idx0 = (int)(key0 & 0xFFFFFFFFULL);
    float s0 = unpack_dist(key0);
    unsigned long long k1 = keysM[idx0];
    int c1 = (int)(k1 & 0xFFFFFFFFULL);
    unsigned long long k2 = keysM[1024 + c1];
    code2_l[tt] = (int)(k2 & 0xFFFFFFFFULL);
    rloss[tt] = s0 + nrm[idx0] + unpack_dist(k1) + nrm[1024 + c1] + unpack_dist(k2);
  }
  __syncthreads();

  float* ob = out + ((size_t)b << 19);
  int code2 = code2_l[tt];
  const float* e2row = emb2 + (size_t)code2 * C_;
  for (int c4 = w * 64; c4 < w * 64 + 64; c4 += 4) {
    float4 ev = *(const float4*)(e2row + c4);
    float evv[4] = {ev.x, ev.y, ev.z, ev.w};
#pragma unroll
    for (int u = 0; u < 4; u++)
      __builtin_nontemporal_store(evv[u], ob + (size_t)(c4 + u) * T_ + t0 + tt);
  }
  if (w == 0) {
    float tot = rloss[tt];
    for (int off = 32; off > 0; off >>= 1)
      tot += __shfl_down(tot, off, 64);
    if (tt == 0) atomicAdd(loss_accum, tot);
  }
  if (tid == 0) {
    __threadfence();
    unsigned old = atomicAdd(counter, 1u);
    if (old == 511u) {
      float L = atomicAdd(loss_accum, 0.0f);   // device-scope read
      out[TOTAL_ELEMS] = 2.0f * L / 8388608.0f;
    }
  }
}

extern "C" void kernel_launch(void* const* d_in, const int* in_sizes, int n_in,
                              void* d_out, int out_size, void* d_ws, size_t ws_size,
                              hipStream_t stream) {
  const float* x  = (const float*)d_in[0];
  const float* e0 = (const float*)d_in[1];
  const float* e1 = (const float*)d_in[2];
  const float* e2 = (const float*)d_in[3];
  float* out = (float*)d_out;
  char* ws = (char*)d_ws;

  unsigned long long* keys  = (unsigned long long*)ws;            // 262144 B
  unsigned long long* keysM = (unsigned long long*)(ws + 262144); // 16384 B
  float* nrm  = (float*)(ws + 278528);                            // 12288 B
  float* loss_accum = (float*)(ws + 290816);                      // 4 B
  unsigned* counter = (unsigned*)(ws + 290820);                   // 4 B
  unsigned short* ebt = (unsigned short*)(ws + 294912);           // 524288 B (frag-linear e0)

  prep_kernel<<<336, 256, 0, stream>>>(e0, e1, e2, nrm, ebt, (uint4*)ws,
                                       loss_accum, counter);
  l0_fused_kernel<<<2048, 256, 0, stream>>>(x, ebt, nrm, keys, loss_accum);
  map_tile_kernel<<<512, 256, 0, stream>>>(e0, e1, e2, nrm, keysM);
  finish_kernel<<<512, 256, 0, stream>>>(e2, keys, keysM, nrm, out, loss_accum, counter);
}

// Round 15
// 98.639 us; speedup vs baseline: 1.8669x; 1.0949x over previous
//
#include <hip/hip_runtime.h>
#include <stdint.h>

// Problem constants
#define B_  16
#define C_  256
#define T_  2048
#define K_  1024
#define TOTAL_ELEMS 8388608   // B*C*T

typedef short bf16x8 __attribute__((ext_vector_type(8)));
typedef float f32x4 __attribute__((ext_vector_type(4)));

// ---------- packed (dist, idx) ordering helpers ----------
__device__ __forceinline__ unsigned long long pack_key(float d, int idx) {
  unsigned u = __float_as_uint(d);
  u = (u & 0x80000000u) ? ~u : (u | 0x80000000u);   // monotone map f32 -> u32
  return ((unsigned long long)u << 32) | (unsigned)idx;
}
__device__ __forceinline__ float unpack_dist(unsigned long long key) {
  unsigned du = (unsigned)(key >> 32);
  unsigned bits = (du & 0x80000000u) ? (du ^ 0x80000000u) : ~du;
  return __uint_as_float(bits);
}

__device__ __forceinline__ unsigned short f2bf_rne(float f) {
  unsigned u = __float_as_uint(f);
  unsigned r = u + 0x7FFFu + ((u >> 16) & 1u);
  return (unsigned short)(r >> 16);
}

__device__ __forceinline__ void gload_lds16(const void* g, void* l) {
  __builtin_amdgcn_global_load_lds(
      (const __attribute__((address_space(1))) unsigned int*)g,
      (__attribute__((address_space(3))) unsigned int*)l, 16, 0, 0);
}

// ============ kernel 1: prep (norms/ebt/init) + xpose (x -> frag-linear xTf) ============
// bids 0..11: norms; 12..267: e0->ebt; 268..335: keys 0xFF init + loss/counter zero;
// 336..2383: xpose 64t x 64c tile -> xTf tile-fragment-linear + lossP partial.
// xTf layout (shorts): tile mb (64 rows) base mb*16384; elem (r, c): kk=c>>5, lg=(c>>3)&3,
// j=c&7 at ((kk*4+lg)*64 + r)*8 + j  -> l0's A-stage is a LINEAR 32KB copy.
__global__ __launch_bounds__(256) void prep_xpose_kernel(
    const float* __restrict__ x, const float* __restrict__ e0,
    const float* __restrict__ e1, const float* __restrict__ e2,
    float* __restrict__ nrm, unsigned short* __restrict__ ebt,
    unsigned short* __restrict__ xTf, uint4* __restrict__ keys_region,
    float* __restrict__ lossP, float* __restrict__ loss_accum,
    unsigned* __restrict__ counter) {
  __shared__ float ftile[64][68];
  __shared__ float red4[4];
  int bid = blockIdx.x;
  int tid = threadIdx.x;
  if (bid < 12) {
    int i = bid * 256 + tid;
    const float* e = (i < 1024) ? e0 : (i < 2048) ? e1 : e2;
    const float* p = e + (size_t)(i & 1023) * C_;
    float s = 0.0f;
    for (int c = 0; c < C_; c += 4) {
      float4 v = *(const float4*)(p + c);
      s = fmaf(v.x, v.x, s); s = fmaf(v.y, v.y, s);
      s = fmaf(v.z, v.z, s); s = fmaf(v.w, v.w, s);
    }
    nrm[i] = s;
  } else if (bid < 268) {
    int code = (bid - 12) * 4 + (tid >> 6);
    int c = (tid & 63) * 4;
    float4 v = *(const float4*)(e0 + (size_t)code * C_ + c);
    unsigned lo = (unsigned)f2bf_rne(v.x) | ((unsigned)f2bf_rne(v.y) << 16);
    unsigned hi = (unsigned)f2bf_rne(v.z) | ((unsigned)f2bf_rne(v.w) << 16);
    int kk = c >> 5, lg = (c >> 3) & 3, j = c & 7;
    *(uint2*)(ebt + ((size_t)(kk * 1024 + code) * 4 + lg) * 8 + j) = make_uint2(lo, hi);
  } else if (bid < 336) {
    int i = (bid - 268) * 256 + tid;     // 0..17407: keys + keysM uint4 init
    keys_region[i] = make_uint4(0xFFFFFFFFu, 0xFFFFFFFFu, 0xFFFFFFFFu, 0xFFFFFFFFu);
    if (bid == 268 && tid == 0) { *loss_accum = 0.0f; *counter = 0u; }
  } else {
    int bx = bid - 336;                  // 0..2047
    int b  = bx >> 7;
    int t0 = ((bx >> 2) & 31) << 6;
    int c0 = (bx & 3) << 6;
    int cr = tid >> 4;                   // 0..15
    int t_loc = (tid & 15) * 4;
    const float* src = x + (size_t)b * (C_ * T_) + (size_t)c0 * T_ + t0;
    float sq = 0.0f;
#pragma unroll
    for (int qq = 0; qq < 4; qq++) {
      int c_loc = cr + qq * 16;
      float4 v = *(const float4*)(src + (size_t)c_loc * T_ + t_loc);
      *(float4*)&ftile[c_loc][t_loc] = v;
      sq = fmaf(v.x, v.x, sq); sq = fmaf(v.y, v.y, sq);
      sq = fmaf(v.z, v.z, sq); sq = fmaf(v.w, v.w, sq);
    }
    for (int off = 32; off > 0; off >>= 1) sq += __shfl_down(sq, off, 64);
    if ((tid & 63) == 0) red4[tid >> 6] = sq;
    __syncthreads();
    if (tid == 0) lossP[bx] = red4[0] + red4[1] + red4[2] + red4[3];

    int t_row = tid >> 2;                // 0..63
    int cs = (tid & 3) * 16;             // 0,16,32,48
    unsigned pk[8];
#pragma unroll
    for (int i = 0; i < 8; i++) {
      unsigned short lo = f2bf_rne(ftile[cs + 2 * i][t_row]);
      unsigned short hi = f2bf_rne(ftile[cs + 2 * i + 1][t_row]);
      pk[i] = (unsigned)lo | ((unsigned)hi << 16);
    }
    int mb = b * 32 + (t0 >> 6);
    int kk = (c0 + cs) >> 5, lg0 = ((c0 + cs) >> 3) & 3;
    unsigned short* dst = xTf + (size_t)mb * 16384 +
                          ((size_t)(kk * 4 + lg0) * 64 + t_row) * 8;
    *(uint4*)dst         = make_uint4(pk[0], pk[1], pk[2], pk[3]);
    *(uint4*)(dst + 512) = make_uint4(pk[4], pk[5], pk[6], pk[7]);   // lg0+1 plane
  }
}

// ============ kernel 2: l0 (bids 0..2047) + code-maps (bids 2048..2559) ============
// l0: 512 row-tiles x 4 code-quarters (bid = q*512 + mb -> 4 q-blocks of a tile are
// 512 apart = same XCD, A-tile L2-reuse). Block: 64 rows x 256 codes, 4 waves; wave w
// owns codes [q*256+w*64, +64). A staged via 8 global_load_lds/thread (LINEAR 32KB copy
// of xTf tile), ONE barrier; B in named regs, single-kk double-buffer (r14-proven,
// no spill). acc init = -||e||^2/2 so acc = -s/2; argmin epilogue -> atomicMin keys.
__global__ __launch_bounds__(256, 2) void l0map_kernel(
    const unsigned short* __restrict__ xTf, const unsigned short* __restrict__ ebt,
    const float* __restrict__ e0, const float* __restrict__ e1,
    const float* __restrict__ e2, const float* __restrict__ nrm,
    unsigned long long* __restrict__ keys, unsigned long long* __restrict__ keysM) {
  __shared__ __align__(16) char smem[34816];
  int bid = blockIdx.x;
  int tid = threadIdx.x;

  if (bid < 2048) {
    char* Abuf = smem;
    unsigned long long (*kred)[4] = (unsigned long long(*)[4])(smem + 32768);
    int l = tid & 63, w = tid >> 6;
    int lr = l & 15, lg = l >> 4;
    int q  = bid >> 9;
    int mb = bid & 511;
    int row0 = mb << 6;

    // ---- stage A: linear 32KB copy of xTf tile into LDS ----
    {
      const char* src = (const char*)(xTf + (size_t)mb * 16384);
      int off = tid * 16;
#pragma unroll
      for (int i = 0; i < 8; i++)
        gload_lds16(src + off + i * 4096, Abuf + off + i * 4096);
    }
    __syncthreads();   // compiler drains vmcnt before barrier -> A ready

    const unsigned short* pB = ebt + ((size_t)((q << 8) + w * 64 + lr) * 4 + lg) * 8;

#define LOADB(s, kk_) do {                                                   \
    const unsigned short* q_ = pB + (size_t)(kk_) * 32768;                   \
    s##0 = *(const bf16x8*)(q_);                                             \
    s##1 = *(const bf16x8*)(q_ + 512);                                       \
    s##2 = *(const bf16x8*)(q_ + 1024);                                      \
    s##3 = *(const bf16x8*)(q_ + 1536);                                      \
  } while (0)

#define DOKK(kk_, s) do {                                                    \
    const char* ab_ = Abuf + (size_t)(((kk_) * 4 + lg) * 64 + lr) * 16;      \
    bf16x8 a0_ = *(const bf16x8*)(ab_);                                      \
    bf16x8 a1_ = *(const bf16x8*)(ab_ + 256);                                \
    bf16x8 a2_ = *(const bf16x8*)(ab_ + 512);                                \
    bf16x8 a3_ = *(const bf16x8*)(ab_ + 768);                                \
    acc[0][0] = __builtin_amdgcn_mfma_f32_16x16x32_bf16(a0_, s##0, acc[0][0], 0, 0, 0); \
    acc[1][0] = __builtin_amdgcn_mfma_f32_16x16x32_bf16(a1_, s##0, acc[1][0], 0, 0, 0); \
    acc[2][0] = __builtin_amdgcn_mfma_f32_16x16x32_bf16(a2_, s##0, acc[2][0], 0, 0, 0); \
    acc[3][0] = __builtin_amdgcn_mfma_f32_16x16x32_bf16(a3_, s##0, acc[3][0], 0, 0, 0); \
    acc[0][1] = __builtin_amdgcn_mfma_f32_16x16x32_bf16(a0_, s##1, acc[0][1], 0, 0, 0); \
    acc[1][1] = __builtin_amdgcn_mfma_f32_16x16x32_bf16(a1_, s##1, acc[1][1], 0, 0, 0); \
    acc[2][1] = __builtin_amdgcn_mfma_f32_16x16x32_bf16(a2_, s##1, acc[2][1], 0, 0, 0); \
    acc[3][1] = __builtin_amdgcn_mfma_f32_16x16x32_bf16(a3_, s##1, acc[3][1], 0, 0, 0); \
    acc[0][2] = __builtin_amdgcn_mfma_f32_16x16x32_bf16(a0_, s##2, acc[0][2], 0, 0, 0); \
    acc[1][2] = __builtin_amdgcn_mfma_f32_16x16x32_bf16(a1_, s##2, acc[1][2], 0, 0, 0); \
    acc[2][2] = __builtin_amdgcn_mfma_f32_16x16x32_bf16(a2_, s##2, acc[2][2], 0, 0, 0); \
    acc[3][2] = __builtin_amdgcn_mfma_f32_16x16x32_bf16(a3_, s##2, acc[3][2], 0, 0, 0); \
    acc[0][3] = __builtin_amdgcn_mfma_f32_16x16x32_bf16(a0_, s##3, acc[0][3], 0, 0, 0); \
    acc[1][3] = __builtin_amdgcn_mfma_f32_16x16x32_bf16(a1_, s##3, acc[1][3], 0, 0, 0); \
    acc[2][3] = __builtin_amdgcn_mfma_f32_16x16x32_bf16(a2_, s##3, acc[2][3], 0, 0, 0); \
    acc[3][3] = __builtin_amdgcn_mfma_f32_16x16x32_bf16(a3_, s##3, acc[3][3], 0, 0, 0); \
  } while (0)

    f32x4 acc[4][4];
#pragma unroll
    for (int ni = 0; ni < 4; ni++) {
      float iv = -0.5f * nrm[(q << 8) + w * 64 + ni * 16 + lr];
      f32x4 ivv = {iv, iv, iv, iv};
#pragma unroll
      for (int mi = 0; mi < 4; mi++) acc[mi][ni] = ivv;
    }

    bf16x8 bA0, bA1, bA2, bA3, bB0, bB1, bB2, bB3;
    LOADB(bA, 0);
    LOADB(bB, 1); DOKK(0, bA);
    LOADB(bA, 2); DOKK(1, bB);
    LOADB(bB, 3); DOKK(2, bA);
    LOADB(bA, 4); DOKK(3, bB);
    LOADB(bB, 5); DOKK(4, bA);
    LOADB(bA, 6); DOKK(5, bB);
    LOADB(bB, 7); DOKK(6, bA);
    DOKK(7, bB);
#undef LOADB
#undef DOKK

#pragma unroll
    for (int mi = 0; mi < 4; mi++) {
#pragma unroll
      for (int r = 0; r < 4; r++) {
        unsigned long long best = 0xFFFFFFFFFFFFFFFFULL;
#pragma unroll
        for (int ni = 0; ni < 4; ni++) {
          int code = (q << 8) | (w << 6) | (ni << 4) | lr;
          unsigned long long key = pack_key(-2.0f * acc[mi][ni][r], code);
          if (key < best) best = key;
        }
#pragma unroll
        for (int off = 1; off < 16; off <<= 1) {
          unsigned long long o = __shfl_xor(best, off, 64);
          if (o < best) best = o;
        }
        if (lr == 0) kred[mi * 16 + lg * 4 + r][w] = best;
      }
    }
    __syncthreads();
    if (tid < 64) {
      unsigned long long b0 = kred[tid][0], b1 = kred[tid][1];
      unsigned long long b2 = kred[tid][2], b3 = kred[tid][3];
      if (b1 < b0) b0 = b1;
      if (b3 < b2) b2 = b3;
      atomicMin(&keys[row0 + tid], b0 < b2 ? b0 : b2);
    }
  } else {
    // ---- code-to-code maps: tiled f32 GEMM + argmin ----
    float (*As)[68] = (float(*)[68])smem;
    float (*Bs)[68] = (float(*)[68])(smem + 4352);
    int bidm = bid - 2048;
    int m = bidm >> 8;
    int tb = bidm & 255;
    int ar0 = (tb >> 4) << 6;
    int br0 = (tb & 15) << 6;
    const float* Ap = m ? e1 : e0;
    const float* Bp = m ? e2 : e1;
    const float* nB = nrm + (m + 1) * 1024;

    int ty = tid >> 4, tx = tid & 15;
    int srow = tid >> 2;
    int skp  = (tid & 3) << 2;

    float acc[4][4];
#pragma unroll
    for (int i = 0; i < 4; i++)
#pragma unroll
      for (int j = 0; j < 4; j++) acc[i][j] = 0.0f;

    const float* gA = Ap + (size_t)(ar0 + srow) * C_ + skp;
    const float* gB = Bp + (size_t)(br0 + srow) * C_ + skp;

    for (int kk = 0; kk < C_; kk += 16) {
      float4 av = *(const float4*)(gA + kk);
      float4 bv = *(const float4*)(gB + kk);
      __syncthreads();
      As[skp + 0][srow] = av.x; As[skp + 1][srow] = av.y;
      As[skp + 2][srow] = av.z; As[skp + 3][srow] = av.w;
      Bs[skp + 0][srow] = bv.x; Bs[skp + 1][srow] = bv.y;
      Bs[skp + 2][srow] = bv.z; Bs[skp + 3][srow] = bv.w;
      __syncthreads();
#pragma unroll
      for (int k = 0; k < 16; k++) {
        float4 a4 = *(const float4*)&As[k][ty * 4];
        float4 b4 = *(const float4*)&Bs[k][tx * 4];
        float aa[4] = {a4.x, a4.y, a4.z, a4.w};
        float bb[4] = {b4.x, b4.y, b4.z, b4.w};
#pragma unroll
        for (int i = 0; i < 4; i++)
#pragma unroll
          for (int j = 0; j < 4; j++)
            acc[i][j] = fmaf(aa[i], bb[j], acc[i][j]);
      }
    }

    float nv[4];
#pragma unroll
    for (int j = 0; j < 4; j++) nv[j] = nB[br0 + tx * 4 + j];

#pragma unroll
    for (int i = 0; i < 4; i++) {
      unsigned long long best = 0xFFFFFFFFFFFFFFFFULL;
#pragma unroll
      for (int j = 0; j < 4; j++) {
        int code = br0 + tx * 4 + j;
        float s = nv[j] - 2.0f * acc[i][j];
        unsigned long long key = pack_key(s, code);
        if (key < best) best = key;
      }
#pragma unroll
      for (int off = 1; off < 16; off <<= 1) {
        unsigned long long o = __shfl_xor(best, off, 64);
        if (o < best) best = o;
      }
      if (tx == 0)
        atomicMin(&keysM[m * 1024 + ar0 + ty * 4 + i], best);
    }
  }
}

// ============ kernel 3: gather output + loss terms + lossP fold + finalize ============
__global__ __launch_bounds__(256) void finish_kernel(
    const float* __restrict__ emb2,
    const unsigned long long* __restrict__ keys,
    const unsigned long long* __restrict__ keysM,
    const float* __restrict__ nrm, const float* __restrict__ lossP,
    float* __restrict__ out, float* __restrict__ loss_accum,
    unsigned* __restrict__ counter) {
  __shared__ int code2_l[64];
  __shared__ float rloss[64];
  int tid = threadIdx.x;
  int b  = blockIdx.x >> 5;
  int t0 = (blockIdx.x & 31) << 6;
  int tt = tid & 63, w = tid >> 6;

  if (w == 0) {
    unsigned long long key0 = keys[(size_t)b * T_ + t0 + tt];
    int idx0 = (int)(key0 & 0xFFFFFFFFULL);
    float s0 = unpack_dist(key0);
    unsigned long long k1 = keysM[idx0];
    int c1 = (int)(k1 & 0xFFFFFFFFULL);
    unsigned long long k2 = keysM[1024 + c1];
    code2_l[tt] = (int)(k2 & 0xFFFFFFFFULL);
    rloss[tt] = s0 + nrm[idx0] + unpack_dist(k1) + nrm[1024 + c1] + unpack_dist(k2);
  }
  __syncthreads();

  float* ob = out + ((size_t)b << 19);
  int code2 = code2_l[tt];
  const float* e2row = emb2 + (size_t)code2 * C_;
  for (int c4 = w * 64; c4 < w * 64 + 64; c4 += 4) {
    float4 ev = *(const float4*)(e2row + c4);
    float evv[4] = {ev.x, ev.y, ev.z, ev.w};
#pragma unroll
    for (int u = 0; u < 4; u++)
      __builtin_nontemporal_store(evv[u], ob + (size_t)(c4 + u) * T_ + t0 + tt);
  }
  if (w == 0) {
    float tot = rloss[tt];
    for (int off = 32; off > 0; off >>= 1)
      tot += __shfl_down(tot, off, 64);
    if (tt == 0) {
      int j = blockIdx.x * 4;
      tot += lossP[j] + lossP[j + 1] + lossP[j + 2] + lossP[j + 3];
      atomicAdd(loss_accum, tot);
    }
  }
  if (tid == 0) {
    __threadfence();
    unsigned old = atomicAdd(counter, 1u);
    if (old == 511u) {
      float L = atomicAdd(loss_accum, 0.0f);   // device-scope read
      out[TOTAL_ELEMS] = 2.0f * L / 8388608.0f;
    }
  }
}

extern "C" void kernel_launch(void* const* d_in, const int* in_sizes, int n_in,
                              void* d_out, int out_size, void* d_ws, size_t ws_size,
                              hipStream_t stream) {
  const float* x  = (const float*)d_in[0];
  const float* e0 = (const float*)d_in[1];
  const float* e1 = (const float*)d_in[2];
  const float* e2 = (const float*)d_in[3];
  float* out = (float*)d_out;
  char* ws = (char*)d_ws;

  unsigned long long* keys  = (unsigned long long*)ws;            // 262144 B
  unsigned long long* keysM = (unsigned long long*)(ws + 262144); // 16384 B
  float* nrm  = (float*)(ws + 278528);                            // 12288 B
  float* loss_accum = (float*)(ws + 290816);                      // 4 B
  unsigned* counter = (unsigned*)(ws + 290820);                   // 4 B
  float* lossP = (float*)(ws + 290824);                           // 8192 B
  unsigned short* ebt = (unsigned short*)(ws + 299520);           // 524288 B
  unsigned short* xTf = (unsigned short*)(ws + 823808);           // 16777216 B

  prep_xpose_kernel<<<2384, 256, 0, stream>>>(x, e0, e1, e2, nrm, ebt, xTf,
                                              (uint4*)ws, lossP, loss_accum, counter);
  l0map_kernel<<<2560, 256, 0, stream>>>(xTf, ebt, e0, e1, e2, nrm, keys, keysM);
  finish_kernel<<<512, 256, 0, stream>>>(e2, keys, keysM, nrm, lossP, out,
                                         loss_accum, counter);
}